// Round 1
// baseline (993.356 us; speedup 1.0000x reference)
//
#include <hip/hip_runtime.h>

typedef unsigned short u16;
typedef __attribute__((ext_vector_type(8))) short short8;
typedef __attribute__((ext_vector_type(4))) float f32x4;

static __device__ __forceinline__ float bf2f(u16 u) {
    union { unsigned int u; float f; } c; c.u = ((unsigned int)u) << 16; return c.f;
}
static __device__ __forceinline__ u16 f2bf(float f) {
    union { float f; unsigned int u; } c; c.f = f;
    unsigned int r = (c.u + 0x7fffu + ((c.u >> 16) & 1u)) >> 16;
    return (u16)r;
}

// ---------------- weight fp32 (K,N) -> bf16 transposed (N,K) ----------------
__global__ void wtrans_kernel(const float* __restrict__ W, u16* __restrict__ Wt, int K, int N) {
    __shared__ float t[32][33];
    const int n0 = blockIdx.x * 32, k0 = blockIdx.y * 32;
    for (int i = threadIdx.y; i < 32; i += 8)
        t[i][threadIdx.x] = W[(size_t)(k0 + i) * N + n0 + threadIdx.x];
    __syncthreads();
    for (int i = threadIdx.y; i < 32; i += 8)
        Wt[(size_t)(n0 + i) * K + k0 + threadIdx.x] = f2bf(t[threadIdx.x][i]);
}

// ---------------- layernorm fp32 -> bf16, one row (1024) per block ----------
__global__ __launch_bounds__(256) void ln_kernel(const float* __restrict__ x,
                                                 const float* __restrict__ g,
                                                 const float* __restrict__ b,
                                                 u16* __restrict__ out) {
    const int row = blockIdx.x;
    const float4* xr = (const float4*)(x + (size_t)row * 1024);
    float4 v = xr[threadIdx.x];
    float s = v.x + v.y + v.z + v.w;
    float ss = v.x * v.x + v.y * v.y + v.z * v.z + v.w * v.w;
    #pragma unroll
    for (int o = 32; o; o >>= 1) { s += __shfl_down(s, o); ss += __shfl_down(ss, o); }
    __shared__ float red[8];
    const int lane = threadIdx.x & 63, wave = threadIdx.x >> 6;
    if (lane == 0) { red[wave] = s; red[4 + wave] = ss; }
    __syncthreads();
    float S = red[0] + red[1] + red[2] + red[3];
    float SS = red[4] + red[5] + red[6] + red[7];
    float mu = S * (1.0f / 1024.0f);
    float var = SS * (1.0f / 1024.0f) - mu * mu;
    float rs = rsqrtf(var + 1e-5f);
    float4 gv = ((const float4*)g)[threadIdx.x];
    float4 bv = ((const float4*)b)[threadIdx.x];
    ushort4 o4;
    o4.x = f2bf((v.x - mu) * rs * gv.x + bv.x);
    o4.y = f2bf((v.y - mu) * rs * gv.y + bv.y);
    o4.z = f2bf((v.z - mu) * rs * gv.z + bv.z);
    o4.w = f2bf((v.w - mu) * rs * gv.w + bv.w);
    ((ushort4*)(out + (size_t)row * 1024))[threadIdx.x] = o4;
}

// ---------------- per-token attention (one token per block) -----------------
__global__ __launch_bounds__(256) void attn_kernel(const u16* __restrict__ Q,
                                                   const u16* __restrict__ K,
                                                   const u16* __restrict__ V,
                                                   const float* __restrict__ unc,
                                                   u16* __restrict__ out) {
    __shared__ float qs[1024], ks[1024];
    __shared__ float vt[64 * 17];     // vt[j][h] = v_row[h*64+j]
    __shared__ float sc[64 * 65];     // stride 65: conflict-friendly row & col access
    __shared__ float sinv;
    const int tid = threadIdx.x;
    const size_t base = (size_t)blockIdx.x * 1024;
    #pragma unroll
    for (int e = 0; e < 4; e++) {
        int idx = tid + 256 * e;
        qs[idx] = bf2f(Q[base + idx]);
        ks[idx] = bf2f(K[base + idx]);
        vt[(idx & 63) * 17 + (idx >> 6)] = bf2f(V[base + idx]);
    }
    if (tid == 0) {
        float s = 0.0f;
        for (int h = 0; h < 16; h++) s += unc[h];
        sinv = 1.0f / (8.0f * s);   // sqrt(64) * sum(u)
    }
    __syncthreads();
    // scores: 4x4 register block per thread
    {
        const int i0 = (tid >> 4) * 4, j0 = (tid & 15) * 4;
        float a[4][4];
        #pragma unroll
        for (int di = 0; di < 4; di++)
            #pragma unroll
            for (int dj = 0; dj < 4; dj++) a[di][dj] = 0.0f;
        #pragma unroll
        for (int h = 0; h < 16; h++) {
            float4 qv = *(const float4*)&qs[h * 64 + i0];
            float4 kv = *(const float4*)&ks[h * 64 + j0];
            float q[4] = {qv.x, qv.y, qv.z, qv.w};
            float k[4] = {kv.x, kv.y, kv.z, kv.w};
            #pragma unroll
            for (int di = 0; di < 4; di++)
                #pragma unroll
                for (int dj = 0; dj < 4; dj++) a[di][dj] += q[di] * k[dj];
        }
        float inv = sinv;
        #pragma unroll
        for (int di = 0; di < 4; di++)
            #pragma unroll
            for (int dj = 0; dj < 4; dj++)
                sc[(i0 + di) * 65 + (j0 + dj)] = a[di][dj] * inv;
    }
    __syncthreads();
    // softmax per row (64 rows on 64 threads)
    if (tid < 64) {
        float m = -1e30f;
        for (int j = 0; j < 64; j++) m = fmaxf(m, sc[tid * 65 + j]);
        float s = 0.0f;
        for (int j = 0; j < 64; j++) { float e = __expf(sc[tid * 65 + j] - m); sc[tid * 65 + j] = e; s += e; }
        float r = 1.0f / s;
        for (int j = 0; j < 64; j++) sc[tid * 65 + j] *= r;
    }
    __syncthreads();
    // out[i][h] = sum_j p[i][j] * v[j][h]; merged[h*64+i] = out[i][h]
    {
        const int i = tid & 63, hq = tid >> 6;  // 4 h-values per thread
        float o0 = 0, o1 = 0, o2 = 0, o3 = 0;
        #pragma unroll 8
        for (int j = 0; j < 64; j++) {
            float p = sc[i * 65 + j];
            const float* vr = &vt[j * 17 + hq * 4];
            o0 += p * vr[0]; o1 += p * vr[1]; o2 += p * vr[2]; o3 += p * vr[3];
        }
        out[base + (hq * 4 + 0) * 64 + i] = f2bf(o0);
        out[base + (hq * 4 + 1) * 64 + i] = f2bf(o1);
        out[base + (hq * 4 + 2) * 64 + i] = f2bf(o2);
        out[base + (hq * 4 + 3) * 64 + i] = f2bf(o3);
    }
}

// ---------------- bf16 GEMM: C[M,N] = A[M,K] * Bt[N,K]^T --------------------
// EPI 0: store bf16(acc)            -> outB
// EPI 1: store fp32 acc+bias[n]+res -> outF
// EPI 2: store bf16(gelu(acc+bias)) -> outB
template <int EPI>
__global__ __launch_bounds__(256, 2)
void gemm_kernel(const u16* __restrict__ A, const u16* __restrict__ Bt,
                 const float* __restrict__ bias, const float* __restrict__ res,
                 float* __restrict__ outF, u16* __restrict__ outB,
                 int N, int K) {
    constexpr int LDA = 40;  // 32 + 8 pad (keeps 16B alignment, breaks bank aliasing)
    __shared__ __align__(16) u16 As[128 * LDA];
    __shared__ __align__(16) u16 Bs[128 * LDA];
    const int tid = threadIdx.x;
    const int lane = tid & 63;
    const int wave = tid >> 6;
    const int wm = (wave >> 1) * 64;
    const int wn = (wave & 1) * 64;
    const int m0 = blockIdx.y * 128;
    const int n0 = blockIdx.x * 128;

    f32x4 acc[4][4];
    #pragma unroll
    for (int i = 0; i < 4; i++)
        #pragma unroll
        for (int j = 0; j < 4; j++) acc[i][j] = (f32x4){0.f, 0.f, 0.f, 0.f};

    const int c0 = tid, c1 = tid + 256;  // 512 16B chunks per tile
    const int r0 = c0 >> 2, q0 = c0 & 3;
    const int r1 = c1 >> 2, q1 = c1 & 3;

    for (int k0 = 0; k0 < K; k0 += 32) {
        uint4 a0 = *(const uint4*)(A + (size_t)(m0 + r0) * K + k0 + q0 * 8);
        uint4 a1 = *(const uint4*)(A + (size_t)(m0 + r1) * K + k0 + q1 * 8);
        uint4 b0 = *(const uint4*)(Bt + (size_t)(n0 + r0) * K + k0 + q0 * 8);
        uint4 b1 = *(const uint4*)(Bt + (size_t)(n0 + r1) * K + k0 + q1 * 8);
        __syncthreads();  // previous iter's reads done before overwrite
        *(uint4*)&As[r0 * LDA + q0 * 8] = a0;
        *(uint4*)&As[r1 * LDA + q1 * 8] = a1;
        *(uint4*)&Bs[r0 * LDA + q0 * 8] = b0;
        *(uint4*)&Bs[r1 * LDA + q1 * 8] = b1;
        __syncthreads();
        short8 af[4], bf[4];
        #pragma unroll
        for (int i = 0; i < 4; i++)
            af[i] = *(const short8*)&As[(wm + i * 16 + (lane & 15)) * LDA + (lane >> 4) * 8];
        #pragma unroll
        for (int j = 0; j < 4; j++)
            bf[j] = *(const short8*)&Bs[(wn + j * 16 + (lane & 15)) * LDA + (lane >> 4) * 8];
        #pragma unroll
        for (int i = 0; i < 4; i++)
            #pragma unroll
            for (int j = 0; j < 4; j++)
                acc[i][j] = __builtin_amdgcn_mfma_f32_16x16x32_bf16(af[i], bf[j], acc[i][j], 0, 0, 0);
    }

    const int rbase = (lane >> 4) * 4;
    const int cidx = lane & 15;
    #pragma unroll
    for (int i = 0; i < 4; i++) {
        #pragma unroll
        for (int j = 0; j < 4; j++) {
            const int n = n0 + wn + j * 16 + cidx;
            #pragma unroll
            for (int r = 0; r < 4; r++) {
                const int m = m0 + wm + i * 16 + rbase + r;
                const size_t idx = (size_t)m * N + n;
                float v = acc[i][j][r];
                if (EPI == 0) {
                    outB[idx] = f2bf(v);
                } else if (EPI == 1) {
                    outF[idx] = v + bias[n] + res[idx];
                } else {
                    float t = v + bias[n];
                    t = 0.5f * t * (1.0f + erff(t * 0.70710678118654752f));
                    outB[idx] = f2bf(t);
                }
            }
        }
    }
}

extern "C" void kernel_launch(void* const* d_in, const int* in_sizes, int n_in,
                              void* d_out, int out_size, void* d_ws, size_t ws_size,
                              hipStream_t stream) {
    const float* x    = (const float*)d_in[0];
    const float* unc  = (const float*)d_in[1];
    const float* Wq   = (const float*)d_in[2];
    const float* Wk   = (const float*)d_in[3];
    const float* Wv   = (const float*)d_in[4];
    const float* Wo   = (const float*)d_in[5];
    const float* bo   = (const float*)d_in[6];
    const float* ln1g = (const float*)d_in[7];
    const float* ln1b = (const float*)d_in[8];
    const float* ln2g = (const float*)d_in[9];
    const float* ln2b = (const float*)d_in[10];
    const float* W1   = (const float*)d_in[11];
    const float* b1   = (const float*)d_in[12];
    const float* W2   = (const float*)d_in[13];
    const float* b2   = (const float*)d_in[14];
    float* out = (float*)d_out;

    const int M = 16384;  // 4 * 4096 tokens
    char* ws = (char*)d_ws;
    const size_t MB = 1024ull * 1024ull;
    u16* Wtq  = (u16*)(ws + 0 * MB);    // 1024x1024 bf16, 2MB each
    u16* Wtk  = (u16*)(ws + 2 * MB);
    u16* Wtv  = (u16*)(ws + 4 * MB);
    u16* Wto  = (u16*)(ws + 6 * MB);
    u16* Wt1  = (u16*)(ws + 8 * MB);    // [4096][1024] 8MB
    u16* Wt2  = (u16*)(ws + 16 * MB);   // [1024][4096] 8MB
    u16* Abuf = (u16*)(ws + 24 * MB);   // 16384x1024 bf16 32MB (tmp / merged attn / tmp2)
    u16* Qb   = (u16*)(ws + 56 * MB);   // 32MB
    u16* Kb   = (u16*)(ws + 88 * MB);   // 32MB
    u16* Vb   = (u16*)(ws + 120 * MB);  // 32MB
    u16* FF1  = (u16*)(ws + 56 * MB);   // 8192x4096 bf16 = 64MB, reuses QKV region
    float* x2 = out;                    // fp32 residual lives in d_out

    // weights -> bf16 transposed
    wtrans_kernel<<<dim3(32, 32), dim3(32, 8), 0, stream>>>(Wq, Wtq, 1024, 1024);
    wtrans_kernel<<<dim3(32, 32), dim3(32, 8), 0, stream>>>(Wk, Wtk, 1024, 1024);
    wtrans_kernel<<<dim3(32, 32), dim3(32, 8), 0, stream>>>(Wv, Wtv, 1024, 1024);
    wtrans_kernel<<<dim3(32, 32), dim3(32, 8), 0, stream>>>(Wo, Wto, 1024, 1024);
    wtrans_kernel<<<dim3(128, 32), dim3(32, 8), 0, stream>>>(W1, Wt1, 1024, 4096);
    wtrans_kernel<<<dim3(32, 128), dim3(32, 8), 0, stream>>>(W2, Wt2, 4096, 1024);

    // LN1
    ln_kernel<<<M, 256, 0, stream>>>(x, ln1g, ln1b, Abuf);

    // QKV projections
    gemm_kernel<0><<<dim3(8, 128), 256, 0, stream>>>(Abuf, Wtq, nullptr, nullptr, nullptr, Qb, 1024, 1024);
    gemm_kernel<0><<<dim3(8, 128), 256, 0, stream>>>(Abuf, Wtk, nullptr, nullptr, nullptr, Kb, 1024, 1024);
    gemm_kernel<0><<<dim3(8, 128), 256, 0, stream>>>(Abuf, Wtv, nullptr, nullptr, nullptr, Vb, 1024, 1024);

    // per-token attention -> merged bf16 into Abuf
    attn_kernel<<<M, 256, 0, stream>>>(Qb, Kb, Vb, unc, Abuf);

    // Wo projection + bo + residual(x) -> x2 (fp32, in d_out)
    gemm_kernel<1><<<dim3(8, 128), 256, 0, stream>>>(Abuf, Wto, bo, x, x2, nullptr, 1024, 1024);

    // LN2
    ln_kernel<<<M, 256, 0, stream>>>(x2, ln2g, ln2b, Abuf);

    // FF in 2 chunks of 8192 rows (FF1 buffer reuse)
    for (int c = 0; c < 2; c++) {
        const size_t ro = (size_t)c * 8192;
        gemm_kernel<2><<<dim3(32, 64), 256, 0, stream>>>(Abuf + ro * 1024, Wt1, b1, nullptr,
                                                         nullptr, FF1, 4096, 1024);
        gemm_kernel<1><<<dim3(8, 64), 256, 0, stream>>>(FF1, Wt2, b2, x2 + ro * 1024,
                                                        out + ro * 1024, nullptr, 1024, 4096);
    }
}

// Round 2
// 943.893 us; speedup vs baseline: 1.0524x; 1.0524x over previous
//
#include <hip/hip_runtime.h>

typedef unsigned short u16;
typedef __attribute__((ext_vector_type(8))) short short8;
typedef __attribute__((ext_vector_type(4))) float f32x4;

static __device__ __forceinline__ float bf2f(u16 u) {
    union { unsigned int u; float f; } c; c.u = ((unsigned int)u) << 16; return c.f;
}
static __device__ __forceinline__ u16 f2bf(float f) {
    union { float f; unsigned int u; } c; c.f = f;
    unsigned int r = (c.u + 0x7fffu + ((c.u >> 16) & 1u)) >> 16;
    return (u16)r;
}

// async 16B global -> LDS (wave-uniform base + lane*16; LDS layout must be
// contiguous in lane order — NO inner-dim padding)
static __device__ __forceinline__ void glds16(const u16* g, u16* l) {
    __builtin_amdgcn_global_load_lds((const __attribute__((address_space(1))) unsigned int*)g,
                                     (__attribute__((address_space(3))) unsigned int*)l,
                                     16, 0, 0);
}

// ---------------- weight fp32 (K,N) -> bf16 transposed (N,K) ----------------
__global__ void wtrans_kernel(const float* __restrict__ W, u16* __restrict__ Wt, int K, int N) {
    __shared__ float t[32][33];
    const int n0 = blockIdx.x * 32, k0 = blockIdx.y * 32;
    for (int i = threadIdx.y; i < 32; i += 8)
        t[i][threadIdx.x] = W[(size_t)(k0 + i) * N + n0 + threadIdx.x];
    __syncthreads();
    for (int i = threadIdx.y; i < 32; i += 8)
        Wt[(size_t)(n0 + i) * K + k0 + threadIdx.x] = f2bf(t[threadIdx.x][i]);
}

// ---------------- layernorm fp32 -> bf16, one row (1024) per block ----------
__global__ __launch_bounds__(256) void ln_kernel(const float* __restrict__ x,
                                                 const float* __restrict__ g,
                                                 const float* __restrict__ b,
                                                 u16* __restrict__ out) {
    const int row = blockIdx.x;
    const float4* xr = (const float4*)(x + (size_t)row * 1024);
    float4 v = xr[threadIdx.x];
    float s = v.x + v.y + v.z + v.w;
    float ss = v.x * v.x + v.y * v.y + v.z * v.z + v.w * v.w;
    #pragma unroll
    for (int o = 32; o; o >>= 1) { s += __shfl_down(s, o); ss += __shfl_down(ss, o); }
    __shared__ float red[8];
    const int lane = threadIdx.x & 63, wave = threadIdx.x >> 6;
    if (lane == 0) { red[wave] = s; red[4 + wave] = ss; }
    __syncthreads();
    float S = red[0] + red[1] + red[2] + red[3];
    float SS = red[4] + red[5] + red[6] + red[7];
    float mu = S * (1.0f / 1024.0f);
    float var = SS * (1.0f / 1024.0f) - mu * mu;
    float rs = rsqrtf(var + 1e-5f);
    float4 gv = ((const float4*)g)[threadIdx.x];
    float4 bv = ((const float4*)b)[threadIdx.x];
    ushort4 o4;
    o4.x = f2bf((v.x - mu) * rs * gv.x + bv.x);
    o4.y = f2bf((v.y - mu) * rs * gv.y + bv.y);
    o4.z = f2bf((v.z - mu) * rs * gv.z + bv.z);
    o4.w = f2bf((v.w - mu) * rs * gv.w + bv.w);
    ((ushort4*)(out + (size_t)row * 1024))[threadIdx.x] = o4;
}

// ---------------- per-token attention: one token per WAVE -------------------
// Lane i owns score row i. K/V staged per-wave in LDS [j][h] (stride 16);
// all score/PV reads are wave-uniform broadcasts (conflict-free).
// Softmax is fully lane-local over 64 registers.
__global__ __launch_bounds__(256) void attn_kernel(const u16* __restrict__ Q,
                                                   const u16* __restrict__ K,
                                                   const u16* __restrict__ V,
                                                   const float* __restrict__ unc,
                                                   u16* __restrict__ out) {
    __shared__ float kb[4][1024];  // [wave][j*16+h]
    __shared__ float vb[4][1024];
    const int tid = threadIdx.x;
    const int wave = tid >> 6, lane = tid & 63;
    const size_t base = (size_t)(blockIdx.x * 4 + wave) * 1024;

    // fill K,V: lane handles 2 chunks of 8 contiguous elements each
    #pragma unroll
    for (int e2 = 0; e2 < 2; e2++) {
        const int c = lane + 64 * e2;           // chunk id within the row
        const int h = c >> 3, j0 = (c & 7) * 8; // 8 consecutive j, same h
        uint4 kraw = *(const uint4*)(K + base + c * 8);
        uint4 vraw = *(const uint4*)(V + base + c * 8);
        u16 kt[8], vt[8];
        *(uint4*)kt = kraw; *(uint4*)vt = vraw;
        #pragma unroll
        for (int e = 0; e < 8; e++) {
            kb[wave][(j0 + e) * 16 + h] = bf2f(kt[e]);
            vb[wave][(j0 + e) * 16 + h] = bf2f(vt[e]);
        }
    }
    // q row for this lane (coalesced 128B per h)
    float q[16];
    #pragma unroll
    for (int h = 0; h < 16; h++) q[h] = bf2f(Q[base + h * 64 + lane]);
    float su = 0.0f;
    #pragma unroll
    for (int h = 0; h < 16; h++) su += unc[h];
    const float sinv = 1.0f / (8.0f * su);  // sqrt(64) * sum(u)
    __syncthreads();

    // scores row i: s[j] = sum_h q[h] * k[j][h]  (k reads broadcast)
    float s[64];
    #pragma unroll
    for (int j = 0; j < 64; j++) {
        const float4* kr = (const float4*)&kb[wave][j * 16];
        float4 k0 = kr[0], k1 = kr[1], k2 = kr[2], k3 = kr[3];
        float a = q[0] * k0.x + q[1] * k0.y + q[2] * k0.z + q[3] * k0.w;
        a += q[4] * k1.x + q[5] * k1.y + q[6] * k1.z + q[7] * k1.w;
        a += q[8] * k2.x + q[9] * k2.y + q[10] * k2.z + q[11] * k2.w;
        a += q[12] * k3.x + q[13] * k3.y + q[14] * k3.z + q[15] * k3.w;
        s[j] = a;
    }
    // lane-local softmax (scale by sinv > 0 preserves order)
    float m = s[0];
    #pragma unroll
    for (int j = 1; j < 64; j++) m = fmaxf(m, s[j]);
    float sum = 0.0f;
    #pragma unroll
    for (int j = 0; j < 64; j++) { s[j] = __expf((s[j] - m) * sinv); sum += s[j]; }
    const float r = 1.0f / sum;
    // PV: o[h] = sum_j s[j] * v[j][h]  (v reads broadcast)
    float o[16];
    #pragma unroll
    for (int h = 0; h < 16; h++) o[h] = 0.0f;
    #pragma unroll
    for (int j = 0; j < 64; j++) {
        const float p = s[j];
        const float4* vr = (const float4*)&vb[wave][j * 16];
        float4 v0 = vr[0], v1 = vr[1], v2 = vr[2], v3 = vr[3];
        o[0] += p * v0.x; o[1] += p * v0.y; o[2] += p * v0.z; o[3] += p * v0.w;
        o[4] += p * v1.x; o[5] += p * v1.y; o[6] += p * v1.z; o[7] += p * v1.w;
        o[8] += p * v2.x; o[9] += p * v2.y; o[10] += p * v2.z; o[11] += p * v2.w;
        o[12] += p * v3.x; o[13] += p * v3.y; o[14] += p * v3.z; o[15] += p * v3.w;
    }
    #pragma unroll
    for (int h = 0; h < 16; h++) out[base + h * 64 + lane] = f2bf(o[h] * r);
}

// ---------------- bf16 GEMM (m97 structure): C = A[M,K] * Bt[N,K]^T ---------
// EPI 0: store bf16(acc)            -> outB
// EPI 1: store fp32 acc+bias[n]+res -> outF
// EPI 2: store bf16(gelu(acc+bias)) -> outB
template <int EPI>
__global__ __launch_bounds__(256, 2)
void gemm_kernel(const u16* __restrict__ A, const u16* __restrict__ Bt,
                 const float* __restrict__ bias, const float* __restrict__ res,
                 float* __restrict__ outF, u16* __restrict__ outB,
                 int N, int K) {
    // NO padding: global_load_lds requires LDS dest = uniform base + lane*16
    __shared__ __align__(16) u16 As[128 * 32];
    __shared__ __align__(16) u16 Bs[128 * 32];
    const int tid = threadIdx.x;
    const int lane = tid & 63;
    const int wave = tid >> 6;
    const int wm = (wave >> 1) * 64;
    const int wn = (wave & 1) * 64;
    const int m0 = blockIdx.y * 128;
    const int n0 = blockIdx.x * 128;

    f32x4 acc[4][4];
    #pragma unroll
    for (int i = 0; i < 4; i++)
        #pragma unroll
        for (int j = 0; j < 4; j++) acc[i][j] = (f32x4){0.f, 0.f, 0.f, 0.f};

    // 512 16B chunks per 128x32 tile; chunk c -> row c>>2, 16B-quad c&3,
    // LDS elem offset c*8 (contiguous => lane order matches)
    const int c0 = tid, c1 = tid + 256;
    const int r0 = c0 >> 2, q0 = c0 & 3;
    const int r1 = c1 >> 2, q1 = c1 & 3;
    const u16* aP0 = A + (size_t)(m0 + r0) * K + q0 * 8;
    const u16* aP1 = A + (size_t)(m0 + r1) * K + q1 * 8;
    const u16* bP0 = Bt + (size_t)(n0 + r0) * K + q0 * 8;
    const u16* bP1 = Bt + (size_t)(n0 + r1) * K + q1 * 8;

    for (int k0 = 0; k0 < K; k0 += 32) {
        __syncthreads();  // prior iter's ds_reads done before async overwrite
        glds16(aP0 + k0, &As[c0 * 8]);
        glds16(aP1 + k0, &As[c1 * 8]);
        glds16(bP0 + k0, &Bs[c0 * 8]);
        glds16(bP1 + k0, &Bs[c1 * 8]);
        __syncthreads();  // vmcnt drained at barrier => LDS tile valid
        short8 af[4], bf[4];
        #pragma unroll
        for (int i = 0; i < 4; i++)
            af[i] = *(const short8*)&As[(wm + i * 16 + (lane & 15)) * 32 + (lane >> 4) * 8];
        #pragma unroll
        for (int j = 0; j < 4; j++)
            bf[j] = *(const short8*)&Bs[(wn + j * 16 + (lane & 15)) * 32 + (lane >> 4) * 8];
        #pragma unroll
        for (int i = 0; i < 4; i++)
            #pragma unroll
            for (int j = 0; j < 4; j++)
                acc[i][j] = __builtin_amdgcn_mfma_f32_16x16x32_bf16(af[i], bf[j], acc[i][j], 0, 0, 0);
    }

    const int rbase = (lane >> 4) * 4;
    const int cidx = lane & 15;
    #pragma unroll
    for (int i = 0; i < 4; i++) {
        #pragma unroll
        for (int j = 0; j < 4; j++) {
            const int n = n0 + wn + j * 16 + cidx;
            #pragma unroll
            for (int r = 0; r < 4; r++) {
                const int m = m0 + wm + i * 16 + rbase + r;
                const size_t idx = (size_t)m * N + n;
                float v = acc[i][j][r];
                if (EPI == 0) {
                    outB[idx] = f2bf(v);
                } else if (EPI == 1) {
                    outF[idx] = v + bias[n] + res[idx];
                } else {
                    float t = v + bias[n];
                    t = 0.5f * t * (1.0f + erff(t * 0.70710678118654752f));
                    outB[idx] = f2bf(t);
                }
            }
        }
    }
}

extern "C" void kernel_launch(void* const* d_in, const int* in_sizes, int n_in,
                              void* d_out, int out_size, void* d_ws, size_t ws_size,
                              hipStream_t stream) {
    const float* x    = (const float*)d_in[0];
    const float* unc  = (const float*)d_in[1];
    const float* Wq   = (const float*)d_in[2];
    const float* Wk   = (const float*)d_in[3];
    const float* Wv   = (const float*)d_in[4];
    const float* Wo   = (const float*)d_in[5];
    const float* bo   = (const float*)d_in[6];
    const float* ln1g = (const float*)d_in[7];
    const float* ln1b = (const float*)d_in[8];
    const float* ln2g = (const float*)d_in[9];
    const float* ln2b = (const float*)d_in[10];
    const float* W1   = (const float*)d_in[11];
    const float* b1   = (const float*)d_in[12];
    const float* W2   = (const float*)d_in[13];
    const float* b2   = (const float*)d_in[14];
    float* out = (float*)d_out;

    const int M = 16384;  // 4 * 4096 tokens
    char* ws = (char*)d_ws;
    const size_t MB = 1024ull * 1024ull;
    u16* Wtq  = (u16*)(ws + 0 * MB);
    u16* Wtk  = (u16*)(ws + 2 * MB);
    u16* Wtv  = (u16*)(ws + 4 * MB);
    u16* Wto  = (u16*)(ws + 6 * MB);
    u16* Wt1  = (u16*)(ws + 8 * MB);    // [4096][1024]
    u16* Wt2  = (u16*)(ws + 16 * MB);   // [1024][4096]
    u16* Abuf = (u16*)(ws + 24 * MB);   // 16384x1024 bf16
    u16* Qb   = (u16*)(ws + 56 * MB);
    u16* Kb   = (u16*)(ws + 88 * MB);
    u16* Vb   = (u16*)(ws + 120 * MB);
    u16* FF1  = (u16*)(ws + 56 * MB);   // 8192x4096 bf16, reuses QKV region
    float* x2 = out;                    // fp32 residual lives in d_out

    wtrans_kernel<<<dim3(32, 32), dim3(32, 8), 0, stream>>>(Wq, Wtq, 1024, 1024);
    wtrans_kernel<<<dim3(32, 32), dim3(32, 8), 0, stream>>>(Wk, Wtk, 1024, 1024);
    wtrans_kernel<<<dim3(32, 32), dim3(32, 8), 0, stream>>>(Wv, Wtv, 1024, 1024);
    wtrans_kernel<<<dim3(32, 32), dim3(32, 8), 0, stream>>>(Wo, Wto, 1024, 1024);
    wtrans_kernel<<<dim3(128, 32), dim3(32, 8), 0, stream>>>(W1, Wt1, 1024, 4096);
    wtrans_kernel<<<dim3(32, 128), dim3(32, 8), 0, stream>>>(W2, Wt2, 4096, 1024);

    ln_kernel<<<M, 256, 0, stream>>>(x, ln1g, ln1b, Abuf);

    gemm_kernel<0><<<dim3(8, 128), 256, 0, stream>>>(Abuf, Wtq, nullptr, nullptr, nullptr, Qb, 1024, 1024);
    gemm_kernel<0><<<dim3(8, 128), 256, 0, stream>>>(Abuf, Wtk, nullptr, nullptr, nullptr, Kb, 1024, 1024);
    gemm_kernel<0><<<dim3(8, 128), 256, 0, stream>>>(Abuf, Wtv, nullptr, nullptr, nullptr, Vb, 1024, 1024);

    attn_kernel<<<M / 4, 256, 0, stream>>>(Qb, Kb, Vb, unc, Abuf);

    gemm_kernel<1><<<dim3(8, 128), 256, 0, stream>>>(Abuf, Wto, bo, x, x2, nullptr, 1024, 1024);

    ln_kernel<<<M, 256, 0, stream>>>(x2, ln2g, ln2b, Abuf);

    for (int c = 0; c < 2; c++) {
        const size_t ro = (size_t)c * 8192;
        gemm_kernel<2><<<dim3(32, 64), 256, 0, stream>>>(Abuf + ro * 1024, Wt1, b1, nullptr,
                                                         nullptr, FF1, 4096, 1024);
        gemm_kernel<1><<<dim3(8, 64), 256, 0, stream>>>(FF1, Wt2, b2, x2 + ro * 1024,
                                                        out + ro * 1024, nullptr, 1024, 4096);
    }
}

// Round 4
// 881.361 us; speedup vs baseline: 1.1271x; 1.0709x over previous
//
#include <hip/hip_runtime.h>

typedef unsigned short u16;
typedef __attribute__((ext_vector_type(8))) short short8;
typedef __attribute__((ext_vector_type(4))) float f32x4;

static __device__ __forceinline__ float bf2f(u16 u) {
    union { unsigned int u; float f; } c; c.u = ((unsigned int)u) << 16; return c.f;
}
static __device__ __forceinline__ u16 f2bf(float f) {
    union { float f; unsigned int u; } c; c.f = f;
    unsigned int r = (c.u + 0x7fffu + ((c.u >> 16) & 1u)) >> 16;
    return (u16)r;
}

// async 16B global -> LDS (wave-uniform base + lane*16)
static __device__ __forceinline__ void glds16(const u16* g, u16* l) {
    __builtin_amdgcn_global_load_lds((const __attribute__((address_space(1))) unsigned int*)g,
                                     (__attribute__((address_space(3))) unsigned int*)l,
                                     16, 0, 0);
}

// XOR-swizzled LDS element offset for (row R, 16B-quad Q) of a 128x32 u16 tile.
// Slot c holds chunk (r=c>>2, q=(c&3)^((c>>3)&3)); 16 consecutive rows at a
// fixed Q hit each of the 8 bank-slots exactly 2x -> conflict-free (2-way free).
static __device__ __forceinline__ int swz(int R, int Q) {
    return R * 32 + ((Q ^ ((R >> 1) & 3)) * 8);
}

// ---------------- weight fp32 (K,N) -> bf16 transposed (N,K) ----------------
__global__ void wtrans_kernel(const float* __restrict__ W, u16* __restrict__ Wt, int K, int N) {
    __shared__ float t[32][33];
    const int n0 = blockIdx.x * 32, k0 = blockIdx.y * 32;
    for (int i = threadIdx.y; i < 32; i += 8)
        t[i][threadIdx.x] = W[(size_t)(k0 + i) * N + n0 + threadIdx.x];
    __syncthreads();
    for (int i = threadIdx.y; i < 32; i += 8)
        Wt[(size_t)(n0 + i) * K + k0 + threadIdx.x] = f2bf(t[threadIdx.x][i]);
}

// ---------------- layernorm fp32 -> bf16, one row (1024) per block ----------
__global__ __launch_bounds__(256) void ln_kernel(const float* __restrict__ x,
                                                 const float* __restrict__ g,
                                                 const float* __restrict__ b,
                                                 u16* __restrict__ out) {
    const int row = blockIdx.x;
    const float4* xr = (const float4*)(x + (size_t)row * 1024);
    float4 v = xr[threadIdx.x];
    float s = v.x + v.y + v.z + v.w;
    float ss = v.x * v.x + v.y * v.y + v.z * v.z + v.w * v.w;
    #pragma unroll
    for (int o = 32; o; o >>= 1) { s += __shfl_down(s, o); ss += __shfl_down(ss, o); }
    __shared__ float red[8];
    const int lane = threadIdx.x & 63, wave = threadIdx.x >> 6;
    if (lane == 0) { red[wave] = s; red[4 + wave] = ss; }
    __syncthreads();
    float S = red[0] + red[1] + red[2] + red[3];
    float SS = red[4] + red[5] + red[6] + red[7];
    float mu = S * (1.0f / 1024.0f);
    float var = SS * (1.0f / 1024.0f) - mu * mu;
    float rs = rsqrtf(var + 1e-5f);
    float4 gv = ((const float4*)g)[threadIdx.x];
    float4 bv = ((const float4*)b)[threadIdx.x];
    ushort4 o4;
    o4.x = f2bf((v.x - mu) * rs * gv.x + bv.x);
    o4.y = f2bf((v.y - mu) * rs * gv.y + bv.y);
    o4.z = f2bf((v.z - mu) * rs * gv.z + bv.z);
    o4.w = f2bf((v.w - mu) * rs * gv.w + bv.w);
    ((ushort4*)(out + (size_t)row * 1024))[threadIdx.x] = o4;
}

// ---------------- per-token attention: one token per WAVE -------------------
// QKV packed per token: row stride 3072 (Q at +0, K at +1024, V at +2048).
__global__ __launch_bounds__(256) void attn_kernel(const u16* __restrict__ QKV,
                                                   const float* __restrict__ unc,
                                                   u16* __restrict__ out) {
    __shared__ float kb[4][1024];  // [wave][j*16+h]
    __shared__ float vb[4][1024];
    const int tid = threadIdx.x;
    const int wave = tid >> 6, lane = tid & 63;
    const int tok = blockIdx.x * 4 + wave;
    const size_t baseq = (size_t)tok * 3072;

    #pragma unroll
    for (int e2 = 0; e2 < 2; e2++) {
        const int c = lane + 64 * e2;
        const int h = c >> 3, j0 = (c & 7) * 8;
        uint4 kraw = *(const uint4*)(QKV + baseq + 1024 + c * 8);
        uint4 vraw = *(const uint4*)(QKV + baseq + 2048 + c * 8);
        u16 kt[8], vt[8];
        *(uint4*)kt = kraw; *(uint4*)vt = vraw;
        #pragma unroll
        for (int e = 0; e < 8; e++) {
            kb[wave][(j0 + e) * 16 + h] = bf2f(kt[e]);
            vb[wave][(j0 + e) * 16 + h] = bf2f(vt[e]);
        }
    }
    float q[16];
    #pragma unroll
    for (int h = 0; h < 16; h++) q[h] = bf2f(QKV[baseq + h * 64 + lane]);
    float su = 0.0f;
    #pragma unroll
    for (int h = 0; h < 16; h++) su += unc[h];
    const float sinv = 1.0f / (8.0f * su);  // sqrt(64) * sum(u)
    __syncthreads();

    float s[64];
    #pragma unroll
    for (int j = 0; j < 64; j++) {
        const float4* kr = (const float4*)&kb[wave][j * 16];
        float4 k0 = kr[0], k1 = kr[1], k2 = kr[2], k3 = kr[3];
        float a = q[0] * k0.x + q[1] * k0.y + q[2] * k0.z + q[3] * k0.w;
        a += q[4] * k1.x + q[5] * k1.y + q[6] * k1.z + q[7] * k1.w;
        a += q[8] * k2.x + q[9] * k2.y + q[10] * k2.z + q[11] * k2.w;
        a += q[12] * k3.x + q[13] * k3.y + q[14] * k3.z + q[15] * k3.w;
        s[j] = a;
    }
    float m = s[0];
    #pragma unroll
    for (int j = 1; j < 64; j++) m = fmaxf(m, s[j]);
    float sum = 0.0f;
    #pragma unroll
    for (int j = 0; j < 64; j++) { s[j] = __expf((s[j] - m) * sinv); sum += s[j]; }
    const float r = 1.0f / sum;
    float o[16];
    #pragma unroll
    for (int h = 0; h < 16; h++) o[h] = 0.0f;
    #pragma unroll
    for (int j = 0; j < 64; j++) {
        const float p = s[j];
        const float4* vr = (const float4*)&vb[wave][j * 16];
        float4 v0 = vr[0], v1 = vr[1], v2 = vr[2], v3 = vr[3];
        o[0] += p * v0.x; o[1] += p * v0.y; o[2] += p * v0.z; o[3] += p * v0.w;
        o[4] += p * v1.x; o[5] += p * v1.y; o[6] += p * v1.z; o[7] += p * v1.w;
        o[8] += p * v2.x; o[9] += p * v2.y; o[10] += p * v2.z; o[11] += p * v2.w;
        o[12] += p * v3.x; o[13] += p * v3.y; o[14] += p * v3.z; o[15] += p * v3.w;
    }
    const size_t baso = (size_t)tok * 1024;
    #pragma unroll
    for (int h = 0; h < 16; h++) out[baso + h * 64 + lane] = f2bf(o[h] * r);
}

// ---------------- bf16 GEMM: C[M,N] = A[M,K] * Bt[N,K]^T --------------------
// async glds staging + XOR-swizzled LDS (conflict-free b128 reads)
// EPI 0: bf16(acc) -> outB ; 1: fp32 acc+bias+res -> outF ; 2: bf16(gelu(acc+bias)) -> outB
template <int EPI>
__global__ __launch_bounds__(256, 2)
void gemm_kernel(const u16* __restrict__ A, const u16* __restrict__ Bt,
                 const float* __restrict__ bias, const float* __restrict__ res,
                 float* __restrict__ outF, u16* __restrict__ outB,
                 int N, int K) {
    __shared__ __align__(16) u16 As[128 * 32];
    __shared__ __align__(16) u16 Bs[128 * 32];
    const int tid = threadIdx.x;
    const int lane = tid & 63;
    const int wave = tid >> 6;
    const int wm = (wave >> 1) * 64;
    const int wn = (wave & 1) * 64;
    const int m0 = blockIdx.y * 128;
    const int n0 = blockIdx.x * 128;

    f32x4 acc[4][4];
    #pragma unroll
    for (int i = 0; i < 4; i++)
        #pragma unroll
        for (int j = 0; j < 4; j++) acc[i][j] = (f32x4){0.f, 0.f, 0.f, 0.f};

    // slot c (LDS byte c*16) <- global chunk (row c>>2, quad (c&3)^((c>>3)&3))
    const int c0 = tid, c1 = tid + 256;
    const int r0 = c0 >> 2, q0 = (c0 & 3) ^ ((c0 >> 3) & 3);
    const int r1 = c1 >> 2, q1 = (c1 & 3) ^ ((c1 >> 3) & 3);
    const u16* aP0 = A + (size_t)(m0 + r0) * K + q0 * 8;
    const u16* aP1 = A + (size_t)(m0 + r1) * K + q1 * 8;
    const u16* bP0 = Bt + (size_t)(n0 + r0) * K + q0 * 8;
    const u16* bP1 = Bt + (size_t)(n0 + r1) * K + q1 * 8;

    for (int k0 = 0; k0 < K; k0 += 32) {
        __syncthreads();
        glds16(aP0 + k0, &As[c0 * 8]);
        glds16(aP1 + k0, &As[c1 * 8]);
        glds16(bP0 + k0, &Bs[c0 * 8]);
        glds16(bP1 + k0, &Bs[c1 * 8]);
        __syncthreads();
        short8 af[4], bf[4];
        #pragma unroll
        for (int i = 0; i < 4; i++)
            af[i] = *(const short8*)&As[swz(wm + i * 16 + (lane & 15), lane >> 4)];
        #pragma unroll
        for (int j = 0; j < 4; j++)
            bf[j] = *(const short8*)&Bs[swz(wn + j * 16 + (lane & 15), lane >> 4)];
        #pragma unroll
        for (int i = 0; i < 4; i++)
            #pragma unroll
            for (int j = 0; j < 4; j++)
                acc[i][j] = __builtin_amdgcn_mfma_f32_16x16x32_bf16(af[i], bf[j], acc[i][j], 0, 0, 0);
    }

    const int rbase = (lane >> 4) * 4;
    const int cidx = lane & 15;
    #pragma unroll
    for (int i = 0; i < 4; i++) {
        #pragma unroll
        for (int j = 0; j < 4; j++) {
            const int n = n0 + wn + j * 16 + cidx;
            #pragma unroll
            for (int r = 0; r < 4; r++) {
                const int m = m0 + wm + i * 16 + rbase + r;
                const size_t idx = (size_t)m * N + n;
                float v = acc[i][j][r];
                if (EPI == 0) {
                    outB[idx] = f2bf(v);
                } else if (EPI == 1) {
                    outF[idx] = v + bias[n] + res[idx];
                } else {
                    float t = v + bias[n];
                    t = 0.5f * t * (1.0f + erff(t * 0.70710678118654752f));
                    outB[idx] = f2bf(t);
                }
            }
        }
    }
}

extern "C" void kernel_launch(void* const* d_in, const int* in_sizes, int n_in,
                              void* d_out, int out_size, void* d_ws, size_t ws_size,
                              hipStream_t stream) {
    const float* x    = (const float*)d_in[0];
    const float* unc  = (const float*)d_in[1];
    const float* Wq   = (const float*)d_in[2];
    const float* Wk   = (const float*)d_in[3];
    const float* Wv   = (const float*)d_in[4];
    const float* Wo   = (const float*)d_in[5];
    const float* bo   = (const float*)d_in[6];
    const float* ln1g = (const float*)d_in[7];
    const float* ln1b = (const float*)d_in[8];
    const float* ln2g = (const float*)d_in[9];
    const float* ln2b = (const float*)d_in[10];
    const float* W1   = (const float*)d_in[11];
    const float* b1   = (const float*)d_in[12];
    const float* W2   = (const float*)d_in[13];
    const float* b2   = (const float*)d_in[14];
    float* out = (float*)d_out;

    const int M = 16384;  // 4 * 4096 tokens
    char* ws = (char*)d_ws;
    const size_t MB = 1024ull * 1024ull;
    u16* Wqkv = (u16*)(ws + 0 * MB);    // [3072][1024] bf16: Wq^T | Wk^T | Wv^T
    u16* Wto  = (u16*)(ws + 6 * MB);
    u16* Wt1  = (u16*)(ws + 8 * MB);    // [4096][1024]
    u16* Wt2  = (u16*)(ws + 16 * MB);   // [1024][4096]
    u16* Abuf = (u16*)(ws + 24 * MB);   // 16384x1024 bf16
    u16* QKVb = (u16*)(ws + 56 * MB);   // 16384x3072 bf16 = 96MB (dead after attn)
    u16* FF1  = (u16*)(ws + 56 * MB);   // 8192x4096 bf16 = 64MB, reuses QKV region
    float* x2 = out;                    // fp32 residual lives in d_out

    wtrans_kernel<<<dim3(32, 32), dim3(32, 8), 0, stream>>>(Wq, Wqkv, 1024, 1024);
    wtrans_kernel<<<dim3(32, 32), dim3(32, 8), 0, stream>>>(Wk, Wqkv + 1024 * 1024, 1024, 1024);
    wtrans_kernel<<<dim3(32, 32), dim3(32, 8), 0, stream>>>(Wv, Wqkv + 2048 * 1024, 1024, 1024);
    wtrans_kernel<<<dim3(32, 32), dim3(32, 8), 0, stream>>>(Wo, Wto, 1024, 1024);
    wtrans_kernel<<<dim3(128, 32), dim3(32, 8), 0, stream>>>(W1, Wt1, 1024, 4096);
    wtrans_kernel<<<dim3(32, 128), dim3(32, 8), 0, stream>>>(W2, Wt2, 4096, 1024);

    ln_kernel<<<M, 256, 0, stream>>>(x, ln1g, ln1b, Abuf);

    // fused QKV projection: C[16384][3072]
    gemm_kernel<0><<<dim3(24, 128), 256, 0, stream>>>(Abuf, Wqkv, nullptr, nullptr,
                                                      nullptr, QKVb, 3072, 1024);

    attn_kernel<<<M / 4, 256, 0, stream>>>(QKVb, unc, Abuf);

    gemm_kernel<1><<<dim3(8, 128), 256, 0, stream>>>(Abuf, Wto, bo, x, x2, nullptr, 1024, 1024);

    ln_kernel<<<M, 256, 0, stream>>>(x2, ln2g, ln2b, Abuf);

    // FF in 2 chunks of 8192 rows (R2-proven memory map, no ws_size branch)
    for (int c = 0; c < 2; c++) {
        const size_t ro = (size_t)c * 8192;
        gemm_kernel<2><<<dim3(32, 64), 256, 0, stream>>>(Abuf + ro * 1024, Wt1, b1, nullptr,
                                                         nullptr, FF1, 4096, 1024);
        gemm_kernel<1><<<dim3(8, 64), 256, 0, stream>>>(FF1, Wt2, b2, x2 + ro * 1024,
                                                        out + ro * 1024, nullptr, 1024, 4096);
    }
}

// Round 5
// 726.577 us; speedup vs baseline: 1.3672x; 1.2130x over previous
//
#include <hip/hip_runtime.h>

typedef unsigned short u16;
typedef __attribute__((ext_vector_type(8))) short short8;
typedef __attribute__((ext_vector_type(4))) float f32x4;

static __device__ __forceinline__ float bf2f(u16 u) {
    union { unsigned int u; float f; } c; c.u = ((unsigned int)u) << 16; return c.f;
}
static __device__ __forceinline__ u16 f2bf(float f) {
    union { float f; unsigned int u; } c; c.f = f;
    unsigned int r = (c.u + 0x7fffu + ((c.u >> 16) & 1u)) >> 16;
    return (u16)r;
}

// async 16B global -> LDS (wave-uniform base + lane*16)
static __device__ __forceinline__ void glds16(const u16* g, u16* l) {
    __builtin_amdgcn_global_load_lds((const __attribute__((address_space(1))) unsigned int*)g,
                                     (__attribute__((address_space(3))) unsigned int*)l,
                                     16, 0, 0);
}

// ---------------- all weight transposes in ONE kernel -----------------------
// fp32 W(K,N) -> bf16 Wt(N,K), 32x32 tiles. id ranges: [0,3072) Wq|Wk|Wv packed,
// [3072,4096) Wo, [4096,8192) W1, [8192,12288) W2.
__global__ void wtrans_all(const float* __restrict__ q, const float* __restrict__ k,
                           const float* __restrict__ v, const float* __restrict__ o,
                           const float* __restrict__ w1, const float* __restrict__ w2,
                           u16* __restrict__ tqkv, u16* __restrict__ to_,
                           u16* __restrict__ t1, u16* __restrict__ t2) {
    const int id = blockIdx.x;
    const float* W; u16* D; int K, N, local;
    if (id < 3072) {
        const int which = id >> 10; local = id & 1023;
        W = which == 0 ? q : (which == 1 ? k : v);
        D = tqkv + (size_t)which * 1024 * 1024; K = 1024; N = 1024;
    } else if (id < 4096) { W = o;  D = to_; K = 1024; N = 1024; local = id - 3072; }
    else if (id < 8192)   { W = w1; D = t1;  K = 1024; N = 4096; local = id - 4096; }
    else                  { W = w2; D = t2;  K = 4096; N = 1024; local = id - 8192; }
    const int nx = N / 32;
    const int n0 = (local % nx) * 32, k0 = (local / nx) * 32;
    __shared__ float t[32][33];
    for (int i = threadIdx.y; i < 32; i += 8)
        t[i][threadIdx.x] = W[(size_t)(k0 + i) * N + n0 + threadIdx.x];
    __syncthreads();
    for (int i = threadIdx.y; i < 32; i += 8)
        D[(size_t)(n0 + i) * K + k0 + threadIdx.x] = f2bf(t[threadIdx.x][i]);
}

// ---------------- layernorm (fp32 or bf16 input) -> bf16 --------------------
template <typename TI>
__global__ __launch_bounds__(256) void ln_kernel(const TI* __restrict__ x,
                                                 const float* __restrict__ g,
                                                 const float* __restrict__ b,
                                                 u16* __restrict__ out) {
    const int row = blockIdx.x;
    float4 v;
    if constexpr (sizeof(TI) == 4) {
        v = ((const float4*)((const float*)x + (size_t)row * 1024))[threadIdx.x];
    } else {
        ushort4 u = ((const ushort4*)((const u16*)x + (size_t)row * 1024))[threadIdx.x];
        v = make_float4(bf2f(u.x), bf2f(u.y), bf2f(u.z), bf2f(u.w));
    }
    float s = v.x + v.y + v.z + v.w;
    float ss = v.x * v.x + v.y * v.y + v.z * v.z + v.w * v.w;
    #pragma unroll
    for (int o = 32; o; o >>= 1) { s += __shfl_down(s, o); ss += __shfl_down(ss, o); }
    __shared__ float red[8];
    const int lane = threadIdx.x & 63, wave = threadIdx.x >> 6;
    if (lane == 0) { red[wave] = s; red[4 + wave] = ss; }
    __syncthreads();
    float S = red[0] + red[1] + red[2] + red[3];
    float SS = red[4] + red[5] + red[6] + red[7];
    float mu = S * (1.0f / 1024.0f);
    float var = SS * (1.0f / 1024.0f) - mu * mu;
    float rs = rsqrtf(var + 1e-5f);
    float4 gv = ((const float4*)g)[threadIdx.x];
    float4 bv = ((const float4*)b)[threadIdx.x];
    ushort4 o4;
    o4.x = f2bf((v.x - mu) * rs * gv.x + bv.x);
    o4.y = f2bf((v.y - mu) * rs * gv.y + bv.y);
    o4.z = f2bf((v.z - mu) * rs * gv.z + bv.z);
    o4.w = f2bf((v.w - mu) * rs * gv.w + bv.w);
    ((ushort4*)(out + (size_t)row * 1024))[threadIdx.x] = o4;
}

// ---------------- per-token attention: one token per WAVE -------------------
// QKV packed per token: row stride 3072 (Q at +0, K at +1024, V at +2048).
__global__ __launch_bounds__(256) void attn_kernel(const u16* __restrict__ QKV,
                                                   const float* __restrict__ unc,
                                                   u16* __restrict__ out) {
    __shared__ float kb[4][1024];  // [wave][j*16+h]
    __shared__ float vb[4][1024];
    const int tid = threadIdx.x;
    const int wave = tid >> 6, lane = tid & 63;
    const int tok = blockIdx.x * 4 + wave;
    const size_t baseq = (size_t)tok * 3072;

    #pragma unroll
    for (int e2 = 0; e2 < 2; e2++) {
        const int c = lane + 64 * e2;
        const int h = c >> 3, j0 = (c & 7) * 8;
        uint4 kraw = *(const uint4*)(QKV + baseq + 1024 + c * 8);
        uint4 vraw = *(const uint4*)(QKV + baseq + 2048 + c * 8);
        u16 kt[8], vt[8];
        *(uint4*)kt = kraw; *(uint4*)vt = vraw;
        #pragma unroll
        for (int e = 0; e < 8; e++) {
            kb[wave][(j0 + e) * 16 + h] = bf2f(kt[e]);
            vb[wave][(j0 + e) * 16 + h] = bf2f(vt[e]);
        }
    }
    float q[16];
    #pragma unroll
    for (int h = 0; h < 16; h++) q[h] = bf2f(QKV[baseq + h * 64 + lane]);
    float su = 0.0f;
    #pragma unroll
    for (int h = 0; h < 16; h++) su += unc[h];
    const float sinv = 1.0f / (8.0f * su);  // sqrt(64) * sum(u)
    __syncthreads();

    float s[64];
    #pragma unroll
    for (int j = 0; j < 64; j++) {
        const float4* kr = (const float4*)&kb[wave][j * 16];
        float4 k0 = kr[0], k1 = kr[1], k2 = kr[2], k3 = kr[3];
        float a = q[0] * k0.x + q[1] * k0.y + q[2] * k0.z + q[3] * k0.w;
        a += q[4] * k1.x + q[5] * k1.y + q[6] * k1.z + q[7] * k1.w;
        a += q[8] * k2.x + q[9] * k2.y + q[10] * k2.z + q[11] * k2.w;
        a += q[12] * k3.x + q[13] * k3.y + q[14] * k3.z + q[15] * k3.w;
        s[j] = a;
    }
    float m = s[0];
    #pragma unroll
    for (int j = 1; j < 64; j++) m = fmaxf(m, s[j]);
    float sum = 0.0f;
    #pragma unroll
    for (int j = 0; j < 64; j++) { s[j] = __expf((s[j] - m) * sinv); sum += s[j]; }
    const float r = 1.0f / sum;
    float o[16];
    #pragma unroll
    for (int h = 0; h < 16; h++) o[h] = 0.0f;
    #pragma unroll
    for (int j = 0; j < 64; j++) {
        const float p = s[j];
        const float4* vr = (const float4*)&vb[wave][j * 16];
        float4 v0 = vr[0], v1 = vr[1], v2 = vr[2], v3 = vr[3];
        o[0] += p * v0.x; o[1] += p * v0.y; o[2] += p * v0.z; o[3] += p * v0.w;
        o[4] += p * v1.x; o[5] += p * v1.y; o[6] += p * v1.z; o[7] += p * v1.w;
        o[8] += p * v2.x; o[9] += p * v2.y; o[10] += p * v2.z; o[11] += p * v2.w;
        o[12] += p * v3.x; o[13] += p * v3.y; o[14] += p * v3.z; o[15] += p * v3.w;
    }
    const size_t baso = (size_t)tok * 1024;
    #pragma unroll
    for (int h = 0; h < 16; h++) out[baso + h * 64 + lane] = f2bf(o[h] * r);
}

// ---------------- bf16 GEMM: C[M,N] = A[M,K] * Bt[N,K]^T --------------------
// BK=64 K-loop (half the barriers of BK=32), async glds staging, XOR-swizzled
// LDS: slot c holds chunk (row c>>3, quad (c&7)^((c>>3)&7)); reader offset for
// logical (R,Q) = R*64 + (Q^(R&7))*8 -> uniform bank-slot spread (conflict-free).
// M on blockIdx.x: consecutive blocks share the (small) weight tile for L2.
// EPI 0: bf16(acc) -> outB
// EPI 1: fp32  acc+bias+bf16res -> outF
// EPI 2: bf16(gelu(acc+bias)) -> outB
// EPI 3: bf16(acc+bias+fp32res) -> outB
template <int EPI>
__global__ __launch_bounds__(256, 2)
void gemm_kernel(const u16* __restrict__ A, const u16* __restrict__ Bt,
                 const float* __restrict__ bias, const void* __restrict__ res,
                 float* __restrict__ outF, u16* __restrict__ outB,
                 int N, int K) {
    __shared__ __align__(16) u16 As[128 * 64];
    __shared__ __align__(16) u16 Bs[128 * 64];
    const int tid = threadIdx.x;
    const int lane = tid & 63;
    const int wave = tid >> 6;
    const int wm = (wave >> 1) * 64;
    const int wn = (wave & 1) * 64;
    const int m0 = blockIdx.x * 128;
    const int n0 = blockIdx.y * 128;

    f32x4 acc[4][4];
    #pragma unroll
    for (int i = 0; i < 4; i++)
        #pragma unroll
        for (int j = 0; j < 4; j++) acc[i][j] = (f32x4){0.f, 0.f, 0.f, 0.f};

    // staging: 1024 chunks of 16B per matrix; thread handles c = tid + 256e
    const u16* aP[4];
    const u16* bP[4];
    #pragma unroll
    for (int e = 0; e < 4; e++) {
        const int c = tid + 256 * e;
        const int r = c >> 3;
        const int qg = (c & 7) ^ (r & 7);
        aP[e] = A + (size_t)(m0 + r) * K + qg * 8;
        bP[e] = Bt + (size_t)(n0 + r) * K + qg * 8;
    }

    for (int k0 = 0; k0 < K; k0 += 64) {
        __syncthreads();  // prior iter's ds_reads done before async overwrite
        #pragma unroll
        for (int e = 0; e < 4; e++) {
            glds16(aP[e] + k0, &As[(tid + 256 * e) * 8]);
            glds16(bP[e] + k0, &Bs[(tid + 256 * e) * 8]);
        }
        __syncthreads();  // vmcnt drained at barrier => LDS tile valid
        #pragma unroll
        for (int kk = 0; kk < 2; kk++) {
            const int Q = (lane >> 4) + kk * 4;
            short8 af[4], bf[4];
            #pragma unroll
            for (int i = 0; i < 4; i++) {
                const int R = wm + i * 16 + (lane & 15);
                af[i] = *(const short8*)&As[R * 64 + ((Q ^ (R & 7)) * 8)];
            }
            #pragma unroll
            for (int j = 0; j < 4; j++) {
                const int R = wn + j * 16 + (lane & 15);
                bf[j] = *(const short8*)&Bs[R * 64 + ((Q ^ (R & 7)) * 8)];
            }
            #pragma unroll
            for (int i = 0; i < 4; i++)
                #pragma unroll
                for (int j = 0; j < 4; j++)
                    acc[i][j] = __builtin_amdgcn_mfma_f32_16x16x32_bf16(af[i], bf[j], acc[i][j], 0, 0, 0);
        }
    }

    const int rbase = (lane >> 4) * 4;
    const int cidx = lane & 15;
    #pragma unroll
    for (int i = 0; i < 4; i++) {
        #pragma unroll
        for (int j = 0; j < 4; j++) {
            const int n = n0 + wn + j * 16 + cidx;
            #pragma unroll
            for (int r = 0; r < 4; r++) {
                const int m = m0 + wm + i * 16 + rbase + r;
                const size_t idx = (size_t)m * N + n;
                float v = acc[i][j][r];
                if (EPI == 0) {
                    outB[idx] = f2bf(v);
                } else if (EPI == 1) {
                    outF[idx] = v + bias[n] + bf2f(((const u16*)res)[idx]);
                } else if (EPI == 2) {
                    float t = v + bias[n];
                    t = 0.5f * t * (1.0f + erff(t * 0.70710678118654752f));
                    outB[idx] = f2bf(t);
                } else {
                    outB[idx] = f2bf(v + bias[n] + ((const float*)res)[idx]);
                }
            }
        }
    }
}

extern "C" void kernel_launch(void* const* d_in, const int* in_sizes, int n_in,
                              void* d_out, int out_size, void* d_ws, size_t ws_size,
                              hipStream_t stream) {
    const float* x    = (const float*)d_in[0];
    const float* unc  = (const float*)d_in[1];
    const float* Wq   = (const float*)d_in[2];
    const float* Wk   = (const float*)d_in[3];
    const float* Wv   = (const float*)d_in[4];
    const float* Wo   = (const float*)d_in[5];
    const float* bo   = (const float*)d_in[6];
    const float* ln1g = (const float*)d_in[7];
    const float* ln1b = (const float*)d_in[8];
    const float* ln2g = (const float*)d_in[9];
    const float* ln2b = (const float*)d_in[10];
    const float* W1   = (const float*)d_in[11];
    const float* b1   = (const float*)d_in[12];
    const float* W2   = (const float*)d_in[13];
    const float* b2   = (const float*)d_in[14];
    float* out = (float*)d_out;

    const int M = 16384;  // 4 * 4096 tokens
    char* ws = (char*)d_ws;
    const size_t MB = 1024ull * 1024ull;
    u16* Wqkv = (u16*)(ws + 0 * MB);    // [3072][1024] bf16: Wq^T | Wk^T | Wv^T
    u16* Wto  = (u16*)(ws + 6 * MB);
    u16* Wt1  = (u16*)(ws + 8 * MB);    // [4096][1024]
    u16* Wt2  = (u16*)(ws + 16 * MB);   // [1024][4096]
    u16* Abuf = (u16*)(ws + 24 * MB);   // 16384x1024 bf16 (tmp / attn-out / tmp2)
    u16* QKVb = (u16*)(ws + 56 * MB);   // 16384x3072 bf16 = 96MB (dead after attn)
    u16* Xr   = (u16*)(ws + 56 * MB);   // bf16 residual x2, 32MB (overwrites dead QKVb)
    u16* FF1  = (u16*)(ws + 88 * MB);   // 8192x4096 bf16 = 64MB (dead QKVb region)
    // footprint 152MB — identical to the R2/R4-proven map; d_out never read as scratch

    wtrans_all<<<12288, dim3(32, 8), 0, stream>>>(Wq, Wk, Wv, Wo, W1, W2,
                                                  Wqkv, Wto, Wt1, Wt2);

    ln_kernel<float><<<M, 256, 0, stream>>>(x, ln1g, ln1b, Abuf);

    // fused QKV projection: C[16384][3072]
    gemm_kernel<0><<<dim3(128, 24), 256, 0, stream>>>(Abuf, Wqkv, nullptr, nullptr,
                                                      nullptr, QKVb, 3072, 1024);

    attn_kernel<<<M / 4, 256, 0, stream>>>(QKVb, unc, Abuf);

    // Wo projection + bo + residual(x fp32) -> bf16 x2 (Xr)
    gemm_kernel<3><<<dim3(128, 8), 256, 0, stream>>>(Abuf, Wto, bo, x, nullptr, Xr, 1024, 1024);

    ln_kernel<u16><<<M, 256, 0, stream>>>(Xr, ln2g, ln2b, Abuf);

    // FF in 2 chunks of 8192 rows
    for (int c = 0; c < 2; c++) {
        const size_t ro = (size_t)c * 8192;
        gemm_kernel<2><<<dim3(64, 32), 256, 0, stream>>>(Abuf + ro * 1024, Wt1, b1, nullptr,
                                                         nullptr, FF1, 4096, 1024);
        gemm_kernel<1><<<dim3(64, 8), 256, 0, stream>>>(FF1, Wt2, b2, Xr + ro * 1024,
                                                        out + ro * 1024, nullptr, 1024, 4096);
    }
}